// Round 14
// baseline (39.510 us; speedup 1.0000x reference)
//
#include <hip/hip_runtime.h>
#include <hip/hip_fp16.h>

#define HW 196
#define C  384
#define CF4 (C/4)          // 96 float4 per row
#define TK 98
#define NT 512
#define NWAVE (NT/64)      // 8

__global__ __launch_bounds__(NT, 4) void sampling_kernel(
    const float* __restrict__ token,
    const float* __restrict__ feature,
    float* __restrict__ out)
{
    // fp16 stash of rows 0..97 (73.5 KB); part[] aliased in after a barrier.
    __shared__ __align__(16) unsigned char stash_raw[TK * C * 2];
    __shared__ float tokLds[C];
    __shared__ float score[HW];
    __shared__ float selW[TK];
    __shared__ int   selIdx[TK];
    __shared__ float wsum[NWAVE];
    // union: rank2 (select phase) / partition lists (pass-2 phase)
    __shared__ int   uni[2 * HW];           // 392 ints = 1568 B
    __shared__ int   cntG;
    __shared__ float s_max, s_winv;

    __half (*feat16)[C] = (__half(*)[C])stash_raw;
    float  (*part)[C]   = (float(*)[C])stash_raw;   // aliased, barrier-fenced

    int*   rank2 = uni;                      // phase: rank/select
    int*   lIdx  = uni;                      // phase: pass-2 (stash rows)
    int*   gIdx  = uni + TK;                 //        pass-2 (global rows)
    float* lW    = (float*)(uni + 2 * TK);
    float* gW    = (float*)(uni + 3 * TK);

    const int tid  = threadIdx.x;
    const int wave = tid >> 6;
    const int lane = tid & 63;
    const int l8   = lane & 7;
    const int g8   = lane >> 3;
    const int pair = blockIdx.x;

    const float* tokp = token + (size_t)pair * C;
    const float4* f4base = (const float4*)(feature + (size_t)pair * (HW * C));
    const float4* t4 = (const float4*)tokLds;

    for (int i = tid; i < C; i += NT) tokLds[i] = tokp[i];
    __syncthreads();

    float4 tok[12];
    #pragma unroll
    for (int k = 0; k < 12; ++k) tok[k] = t4[l8 + 8 * k];

    const float scale = 0.05103103630798288f;  // 384^-0.5

    // ---- pass 1: 8-lane group per row; 3 balanced iters + tail.
    // 12 independent float4 loads/lane; rows < 98 stashed to LDS as fp16.
    #pragma unroll
    for (int it = 0; it < 3; ++it) {
        const int r = it * 64 + wave * 8 + g8;          // 0..191
        const float4* fr = f4base + (size_t)r * CF4 + l8;
        float4 a[12];
        #pragma unroll
        for (int k = 0; k < 12; ++k) a[k] = fr[8 * k];
        float4 acc = make_float4(0.f, 0.f, 0.f, 0.f);
        #pragma unroll
        for (int k = 0; k < 12; ++k) {
            acc.x += a[k].x * tok[k].x; acc.y += a[k].y * tok[k].y;
            acc.z += a[k].z * tok[k].z; acc.w += a[k].w * tok[k].w;
        }
        if (r < TK) {
            #pragma unroll
            for (int k = 0; k < 12; ++k) {
                union { uint2 u; __half2 h[2]; } W;
                W.h[0] = __floats2half2_rn(a[k].x, a[k].y);
                W.h[1] = __floats2half2_rn(a[k].z, a[k].w);
                *(uint2*)&feat16[r][4 * l8 + 32 * k] = W.u;
            }
        }
        float s = (acc.x + acc.y) + (acc.z + acc.w);
        s += __shfl_xor(s, 1, 64);
        s += __shfl_xor(s, 2, 64);
        s += __shfl_xor(s, 4, 64);
        if (l8 == 0) score[r] = s * scale;
    }
    if (wave < 4 && g8 == 0) {                          // tail rows 192..195
        const int r = 192 + wave;
        const float4* fr = f4base + (size_t)r * CF4 + l8;
        float4 acc = make_float4(0.f, 0.f, 0.f, 0.f);
        #pragma unroll
        for (int k = 0; k < 12; ++k) {
            float4 a = fr[8 * k];
            acc.x += a.x * tok[k].x; acc.y += a.y * tok[k].y;
            acc.z += a.z * tok[k].z; acc.w += a.w * tok[k].w;
        }
        float s = (acc.x + acc.y) + (acc.z + acc.w);
        s += __shfl_xor(s, 1, 64);
        s += __shfl_xor(s, 2, 64);
        s += __shfl_xor(s, 4, 64);
        if (l8 == 0) score[r] = s * scale;
    }
    __syncthreads();

    // ---- rank-count (threads 0..391, half-range each); wave 7: max ----
    if (tid < 2 * HW) {
        const int i = tid >> 1, h = tid & 1;
        const float si = score[i];
        int cnt = 0;
        const int j0 = h * (HW / 2);
        for (int j = j0; j < j0 + HW / 2; ++j) {
            const float sj = score[j];
            cnt += (int)((sj > si) | ((sj == si) & (j < i)));
        }
        rank2[tid] = cnt;
    } else if (wave == NWAVE - 1) {
        float m = -3.4e38f;
        for (int i = lane; i < HW; i += 64) m = fmaxf(m, score[i]);
        #pragma unroll
        for (int off = 32; off > 0; off >>= 1)
            m = fmaxf(m, __shfl_xor(m, off, 64));
        if (lane == 0) s_max = m;
    }
    __syncthreads();

    // ---- select + compact (softmax denom cancels: w = exp(s - max)) ----
    float w = 0.f;
    if (tid < HW) {
        const int rank = rank2[2 * tid] + rank2[2 * tid + 1];
        if (rank < TK) {
            w = __expf(score[tid] - s_max);
            selIdx[rank] = tid;
            selW[rank]  = w;
        }
    }
    #pragma unroll
    for (int off = 32; off > 0; off >>= 1) w += __shfl_xor(w, off, 64);
    if (lane == 0) wsum[wave] = w;
    __syncthreads();   // rank2 dead from here; uni reused for lists

    // ---- partition: split selected rows into stash-resident (idx<98)
    // vs global (idx>=98), deterministic (no atomics). tid NT-1: s_winv. ----
    if (tid < TK) {
        const int  r   = selIdx[tid];
        const bool isG = (r >= TK);
        int pos = 0, cg = 0;
        for (int j = 0; j < TK; ++j) {
            const bool g = (selIdx[j] >= TK);
            cg  += (int)g;
            pos += (int)((j < tid) & (g == isG));
        }
        if (isG) { gIdx[pos] = r; gW[pos] = selW[tid]; }
        else     { lIdx[pos] = r; lW[pos] = selW[tid]; }
        if (tid == 0) cntG = cg;
    } else if (tid == NT - 1) {
        float s = 0.f;
        #pragma unroll
        for (int i = 0; i < NWAVE; ++i) s += wsum[i];
        s_winv = 1.f / s;
    }
    __syncthreads();

    // ---- pass 2a: global rows, 4-row batches -> 8 independent float4
    // loads in flight per lane (breaks the per-row latency chain). ----
    float4 acc_a = make_float4(0.f, 0.f, 0.f, 0.f);
    float4 acc_b = make_float4(0.f, 0.f, 0.f, 0.f);
    const int cg = cntG;
    for (int base = wave * 4; base < cg; base += 4 * NWAVE) {
        const int n = min(4, cg - base);               // wave-uniform
        if (n == 4) {
            const int r0 = gIdx[base + 0], r1 = gIdx[base + 1];
            const int r2 = gIdx[base + 2], r3 = gIdx[base + 3];
            const float w0 = gW[base + 0], w1 = gW[base + 1];
            const float w2 = gW[base + 2], w3 = gW[base + 3];
            const float4* p0 = f4base + (size_t)r0 * CF4;
            const float4* p1 = f4base + (size_t)r1 * CF4;
            const float4* p2 = f4base + (size_t)r2 * CF4;
            const float4* p3 = f4base + (size_t)r3 * CF4;
            float4 A0 = p0[lane], A1 = p1[lane], A2 = p2[lane], A3 = p3[lane];
            float4 B0, B1, B2, B3;
            if (lane < 32) {
                B0 = p0[64 + lane]; B1 = p1[64 + lane];
                B2 = p2[64 + lane]; B3 = p3[64 + lane];
            }
            acc_a.x += w0*A0.x + w1*A1.x + w2*A2.x + w3*A3.x;
            acc_a.y += w0*A0.y + w1*A1.y + w2*A2.y + w3*A3.y;
            acc_a.z += w0*A0.z + w1*A1.z + w2*A2.z + w3*A3.z;
            acc_a.w += w0*A0.w + w1*A1.w + w2*A2.w + w3*A3.w;
            if (lane < 32) {
                acc_b.x += w0*B0.x + w1*B1.x + w2*B2.x + w3*B3.x;
                acc_b.y += w0*B0.y + w1*B1.y + w2*B2.y + w3*B3.y;
                acc_b.z += w0*B0.z + w1*B1.z + w2*B2.z + w3*B3.z;
                acc_b.w += w0*B0.w + w1*B1.w + w2*B2.w + w3*B3.w;
            }
        } else {
            for (int k = 0; k < n; ++k) {
                const int   r   = gIdx[base + k];
                const float wgt = gW[base + k];
                const float4* p = f4base + (size_t)r * CF4;
                float4 A = p[lane];
                acc_a.x += wgt*A.x; acc_a.y += wgt*A.y;
                acc_a.z += wgt*A.z; acc_a.w += wgt*A.w;
                if (lane < 32) {
                    float4 B = p[64 + lane];
                    acc_b.x += wgt*B.x; acc_b.y += wgt*B.y;
                    acc_b.z += wgt*B.z; acc_b.w += wgt*B.w;
                }
            }
        }
    }

    // ---- pass 2b: stash rows from LDS (uint2 fp16 reads) ----
    const int cl = TK - cg;
    for (int j = wave; j < cl; j += NWAVE) {
        const int   r   = lIdx[j];                     // 0..97 == stash row
        const float wgt = lW[j];
        union { uint2 u; __half2 h[2]; } U;
        U.u = *(const uint2*)&feat16[r][4 * lane];
        float2 f0 = __half22float2(U.h[0]);
        float2 f1 = __half22float2(U.h[1]);
        acc_a.x += wgt * f0.x; acc_a.y += wgt * f0.y;
        acc_a.z += wgt * f1.x; acc_a.w += wgt * f1.y;
        if (lane < 32) {
            union { uint2 u; __half2 h[2]; } V;
            V.u = *(const uint2*)&feat16[r][256 + 4 * lane];
            float2 g0 = __half22float2(V.h[0]);
            float2 g1 = __half22float2(V.h[1]);
            acc_b.x += wgt * g0.x; acc_b.y += wgt * g0.y;
            acc_b.z += wgt * g1.x; acc_b.w += wgt * g1.y;
        }
    }
    // all stash reads complete before region is reused for partials
    __syncthreads();

    float4* pw = (float4*)&part[wave][0];
    pw[lane] = acc_a;
    if (lane < 32) pw[64 + lane] = acc_b;
    __syncthreads();

    // ---- 8-way cross-wave reduction, coalesced store ----
    if (tid < C) {
        float s = 0.f;
        #pragma unroll
        for (int wv = 0; wv < NWAVE; ++wv) s += part[wv][tid];
        out[(size_t)pair * C + tid] = s * s_winv;
    }
}

extern "C" void kernel_launch(void* const* d_in, const int* in_sizes, int n_in,
                              void* d_out, int out_size, void* d_ws, size_t ws_size,
                              hipStream_t stream) {
    const float* token   = (const float*)d_in[0];
    const float* feature = (const float*)d_in[1];
    float* out = (float*)d_out;
    const int pairs = in_sizes[0] / C;   // 8*16*4 = 512
    sampling_kernel<<<pairs, NT, 0, stream>>>(token, feature, out);
}

// Round 15
// 37.213 us; speedup vs baseline: 1.0618x; 1.0618x over previous
//
#include <hip/hip_runtime.h>
#include <hip/hip_fp16.h>

#define HW 196
#define C  384
#define CF4 (C/4)          // 96 float4 per row
#define TK 98
#define NT 512
#define NWAVE (NT/64)      // 8

__global__ __launch_bounds__(NT, 4) void sampling_kernel(
    const float* __restrict__ token,
    const float* __restrict__ feature,
    float* __restrict__ out)
{
    // fp16 stash of rows 0..97 (73.5 KB); part[] aliased in after a barrier.
    __shared__ __align__(16) unsigned char stash_raw[TK * C * 2];
    __shared__ float tokLds[C];
    __shared__ float score[HW];
    __shared__ float selW[TK];
    __shared__ int   selIdx[TK];
    __shared__ float wsum[NWAVE];
    __shared__ int   rank2[2 * HW];
    __shared__ float s_winv;

    __half (*feat16)[C] = (__half(*)[C])stash_raw;
    float  (*part)[C]   = (float(*)[C])stash_raw;   // aliased, barrier-fenced

    const int tid  = threadIdx.x;
    const int wave = tid >> 6;
    const int lane = tid & 63;
    const int l8   = lane & 7;         // sub-lane within 8-lane group
    const int g8   = lane >> 3;        // group 0..7 within wave
    const int pair = blockIdx.x;

    const float* tokp  = token   + (size_t)pair * C;
    const float4* f4base = (const float4*)(feature + (size_t)pair * (HW * C));
    const float4* t4 = (const float4*)tokLds;

    for (int i = tid; i < C; i += NT) tokLds[i] = tokp[i];
    __syncthreads();

    // this lane's token column-slice in registers
    float4 tok[12];
    #pragma unroll
    for (int k = 0; k < 12; ++k) tok[k] = t4[l8 + 8 * k];

    const float scale = 0.05103103630798288f;  // 384^-0.5

    // ---- pass 1: 8-lane group per row; 64 groups -> 3 balanced iters.
    // 12 independent float4 loads/lane; rows < 98 stashed to LDS as fp16.
    #pragma unroll
    for (int it = 0; it < 3; ++it) {
        const int r = it * 64 + wave * 8 + g8;          // 0..191, balanced
        const float4* fr = f4base + (size_t)r * CF4 + l8;
        float4 a[12];
        #pragma unroll
        for (int k = 0; k < 12; ++k) a[k] = fr[8 * k];
        float4 acc = make_float4(0.f, 0.f, 0.f, 0.f);
        #pragma unroll
        for (int k = 0; k < 12; ++k) {
            acc.x += a[k].x * tok[k].x; acc.y += a[k].y * tok[k].y;
            acc.z += a[k].z * tok[k].z; acc.w += a[k].w * tok[k].w;
        }
        if (r < TK) {
            #pragma unroll
            for (int k = 0; k < 12; ++k) {
                union { uint2 u; __half2 h[2]; } W;
                W.h[0] = __floats2half2_rn(a[k].x, a[k].y);
                W.h[1] = __floats2half2_rn(a[k].z, a[k].w);
                *(uint2*)&feat16[r][4 * l8 + 32 * k] = W.u;
            }
        }
        float s = (acc.x + acc.y) + (acc.z + acc.w);
        s += __shfl_xor(s, 1, 64);
        s += __shfl_xor(s, 2, 64);
        s += __shfl_xor(s, 4, 64);
        if (l8 == 0) score[r] = s * scale;
    }
    // tail rows 192..195 (all >= 98, no stash)
    if (wave < 4 && g8 == 0) {
        const int r = 192 + wave;
        const float4* fr = f4base + (size_t)r * CF4 + l8;
        float4 acc = make_float4(0.f, 0.f, 0.f, 0.f);
        #pragma unroll
        for (int k = 0; k < 12; ++k) {
            float4 a = fr[8 * k];
            acc.x += a.x * tok[k].x; acc.y += a.y * tok[k].y;
            acc.z += a.z * tok[k].z; acc.w += a.w * tok[k].w;
        }
        float s = (acc.x + acc.y) + (acc.z + acc.w);
        s += __shfl_xor(s, 1, 64);
        s += __shfl_xor(s, 2, 64);
        s += __shfl_xor(s, 4, 64);
        if (l8 == 0) score[r] = s * scale;
    }
    __syncthreads();

    // ---- rank-count (threads 0..391, half-range each). No max phase:
    // exp(s) without shift is safe (s ~ N(0,1)) and the shift cancels
    // identically under the final renormalization. ----
    if (tid < 2 * HW) {
        const int i = tid >> 1, h = tid & 1;
        const float si = score[i];
        int cnt = 0;
        const int j0 = h * (HW / 2);
        for (int j = j0; j < j0 + HW / 2; ++j) {
            const float sj = score[j];
            cnt += (int)((sj > si) | ((sj == si) & (j < i)));
        }
        rank2[tid] = cnt;
    }
    __syncthreads();

    // ---- select + compact (softmax denom cancels: w = exp(s)) ----
    float w = 0.f;
    if (tid < HW) {
        const int rank = rank2[2 * tid] + rank2[2 * tid + 1];
        if (rank < TK) {
            w = __expf(score[tid]);
            selIdx[rank] = tid;
            selW[rank]  = w;
        }
    }
    #pragma unroll
    for (int off = 32; off > 0; off >>= 1) w += __shfl_xor(w, off, 64);
    if (lane == 0) wsum[wave] = w;
    __syncthreads();
    if (tid == 0) {
        float s = 0.f;
        #pragma unroll
        for (int i = 0; i < NWAVE; ++i) s += wsum[i];
        s_winv = 1.f / s;
    }
    __syncthreads();

    // ---- pass 2: weighted sum over 98 selected rows.
    // Contiguous per-wave chunks + one-ahead (idx,w) prefetch.
    // idx < 98 -> fp16 LDS stash; idx >= 98 -> global (L3-warm).
    // Row index is wave-uniform -> branch is wave-uniform. ----
    float4 acc_a = make_float4(0.f, 0.f, 0.f, 0.f);
    float4 acc_b = make_float4(0.f, 0.f, 0.f, 0.f);
    {
        const int start = (wave * TK) / NWAVE;
        const int end   = ((wave + 1) * TK) / NWAVE;
        int   r_cur = selIdx[start];
        float w_cur = selW[start];
        for (int j = start; j < end; ++j) {
            int   r_nxt = 0;
            float w_nxt = 0.f;
            if (j + 1 < end) { r_nxt = selIdx[j + 1]; w_nxt = selW[j + 1]; }
            if (r_cur < TK) {
                union { uint2 u; __half2 h[2]; } U;
                U.u = *(const uint2*)&feat16[r_cur][4 * lane];
                float2 f0 = __half22float2(U.h[0]);
                float2 f1 = __half22float2(U.h[1]);
                acc_a.x += w_cur * f0.x; acc_a.y += w_cur * f0.y;
                acc_a.z += w_cur * f1.x; acc_a.w += w_cur * f1.y;
                if (lane < 32) {
                    union { uint2 u; __half2 h[2]; } V;
                    V.u = *(const uint2*)&feat16[r_cur][256 + 4 * lane];
                    float2 g0 = __half22float2(V.h[0]);
                    float2 g1 = __half22float2(V.h[1]);
                    acc_b.x += w_cur * g0.x; acc_b.y += w_cur * g0.y;
                    acc_b.z += w_cur * g1.x; acc_b.w += w_cur * g1.y;
                }
            } else {
                const float4* f4 = f4base + (size_t)r_cur * CF4;
                float4 aa = f4[lane];
                acc_a.x += w_cur * aa.x; acc_a.y += w_cur * aa.y;
                acc_a.z += w_cur * aa.z; acc_a.w += w_cur * aa.w;
                if (lane < 32) {
                    float4 bb = f4[64 + lane];
                    acc_b.x += w_cur * bb.x; acc_b.y += w_cur * bb.y;
                    acc_b.z += w_cur * bb.z; acc_b.w += w_cur * bb.w;
                }
            }
            r_cur = r_nxt;
            w_cur = w_nxt;
        }
    }
    // all stash reads complete before the region is reused for partials
    __syncthreads();

    float4* pw = (float4*)&part[wave][0];
    pw[lane] = acc_a;
    if (lane < 32) pw[64 + lane] = acc_b;
    __syncthreads();

    // ---- 8-way cross-wave reduction, coalesced store ----
    if (tid < C) {
        float s = 0.f;
        #pragma unroll
        for (int wv = 0; wv < NWAVE; ++wv) s += part[wv][tid];
        out[(size_t)pair * C + tid] = s * s_winv;
    }
}

extern "C" void kernel_launch(void* const* d_in, const int* in_sizes, int n_in,
                              void* d_out, int out_size, void* d_ws, size_t ws_size,
                              hipStream_t stream) {
    const float* token   = (const float*)d_in[0];
    const float* feature = (const float*)d_in[1];
    float* out = (float*)d_out;
    const int pairs = in_sizes[0] / C;   // 8*16*4 = 512
    sampling_kernel<<<pairs, NT, 0, stream>>>(token, feature, out);
}

// Round 16
// 36.878 us; speedup vs baseline: 1.0714x; 1.0091x over previous
//
#include <hip/hip_runtime.h>
#include <hip/hip_fp16.h>

#define HW 196
#define C  384
#define CF4 (C/4)          // 96 float4 per row
#define TK 98
#define NT 512
#define NWAVE (NT/64)      // 8

__global__ __launch_bounds__(NT, 4) void sampling_kernel(
    const float* __restrict__ token,
    const float* __restrict__ feature,
    float* __restrict__ out)
{
    // fp16 stash of rows 0..97 (73.5 KB). Total LDS ~78 KB -> 2 blocks/CU.
    // After pass-2 accumulation this region is reused (post-barrier) for
    // the cross-wave partials.
    __shared__ __align__(16) unsigned char stash_raw[TK * C * 2];
    __shared__ float tokLds[C];
    __shared__ float score[HW];
    __shared__ float selW[TK];
    __shared__ int   selIdx[TK];
    __shared__ float wsum[NWAVE];
    __shared__ int   rank2[2 * HW];
    __shared__ float s_max, s_winv;

    __half (*feat16)[C] = (__half(*)[C])stash_raw;
    float  (*part)[C]   = (float(*)[C])stash_raw;   // aliased, barrier-fenced

    const int tid  = threadIdx.x;
    const int wave = tid >> 6;
    const int lane = tid & 63;
    const int l8   = lane & 7;         // sub-lane within 8-lane group
    const int g8   = lane >> 3;        // group 0..7 within wave
    const int pair = blockIdx.x;

    const float* tokp  = token   + (size_t)pair * C;
    const float* featp = feature + (size_t)pair * (HW * C);
    const float4* f4base = (const float4*)featp;
    const float4* t4     = (const float4*)tokLds;

    // stage token row (384 f32) in LDS
    for (int i = tid; i < C; i += NT) tokLds[i] = tokp[i];
    __syncthreads();

    // this lane's token column-slice in registers: cols 4*l8+32k
    float4 tok[12];
    #pragma unroll
    for (int k = 0; k < 12; ++k) tok[k] = t4[l8 + 8 * k];

    const float scale = 0.05103103630798288f;  // 384^-0.5

    // ---- pass 1: 8-lane group per row; 64 groups -> 3 balanced iters.
    // 12 independent float4 loads/lane; rows < 98 additionally stashed
    // to LDS as fp16 (data already in registers -> free bandwidth-wise).
    #pragma unroll
    for (int it = 0; it < 3; ++it) {
        const int r = it * 64 + wave * 8 + g8;          // 0..191, balanced
        const float4* fr = f4base + (size_t)r * CF4 + l8;
        float4 a[12];
        #pragma unroll
        for (int k = 0; k < 12; ++k) a[k] = fr[8 * k];
        float4 acc = make_float4(0.f, 0.f, 0.f, 0.f);
        #pragma unroll
        for (int k = 0; k < 12; ++k) {
            acc.x += a[k].x * tok[k].x; acc.y += a[k].y * tok[k].y;
            acc.z += a[k].z * tok[k].z; acc.w += a[k].w * tok[k].w;
        }
        if (r < TK) {
            #pragma unroll
            for (int k = 0; k < 12; ++k) {
                union { uint2 u; __half2 h[2]; } W;
                W.h[0] = __floats2half2_rn(a[k].x, a[k].y);
                W.h[1] = __floats2half2_rn(a[k].z, a[k].w);
                *(uint2*)&feat16[r][4 * l8 + 32 * k] = W.u;
            }
        }
        float s = (acc.x + acc.y) + (acc.z + acc.w);
        s += __shfl_xor(s, 1, 64);
        s += __shfl_xor(s, 2, 64);
        s += __shfl_xor(s, 4, 64);
        if (l8 == 0) score[r] = s * scale;
    }
    // tail rows 192..195 (all >= 98, no stash)
    if (wave < 4 && g8 == 0) {
        const int r = 192 + wave;
        const float4* fr = f4base + (size_t)r * CF4 + l8;
        float4 acc = make_float4(0.f, 0.f, 0.f, 0.f);
        #pragma unroll
        for (int k = 0; k < 12; ++k) {
            float4 a = fr[8 * k];
            acc.x += a.x * tok[k].x; acc.y += a.y * tok[k].y;
            acc.z += a.z * tok[k].z; acc.w += a.w * tok[k].w;
        }
        float s = (acc.x + acc.y) + (acc.z + acc.w);
        s += __shfl_xor(s, 1, 64);
        s += __shfl_xor(s, 2, 64);
        s += __shfl_xor(s, 4, 64);
        if (l8 == 0) score[r] = s * scale;
    }
    __syncthreads();

    // ---- concurrent: threads 0..391 rank-count (half-range each);
    //      wave 7 computes the max. ----
    if (tid < 2 * HW) {
        const int i = tid >> 1, h = tid & 1;
        const float si = score[i];
        int cnt = 0;
        const int j0 = h * (HW / 2);
        for (int j = j0; j < j0 + HW / 2; ++j) {
            const float sj = score[j];
            cnt += (int)((sj > si) | ((sj == si) & (j < i)));
        }
        rank2[tid] = cnt;
    } else if (wave == NWAVE - 1) {
        float m = -3.4e38f;
        for (int i = lane; i < HW; i += 64) m = fmaxf(m, score[i]);
        #pragma unroll
        for (int off = 32; off > 0; off >>= 1)
            m = fmaxf(m, __shfl_xor(m, off, 64));
        if (lane == 0) s_max = m;
    }
    __syncthreads();

    // ---- select + compact (softmax denom cancels: w = exp(s - max)) ----
    float w = 0.f;
    if (tid < HW) {
        const int rank = rank2[2 * tid] + rank2[2 * tid + 1];
        if (rank < TK) {
            w = __expf(score[tid] - s_max);
            selIdx[rank] = tid;
            selW[rank]  = w;
        }
    }
    #pragma unroll
    for (int off = 32; off > 0; off >>= 1) w += __shfl_xor(w, off, 64);
    if (lane == 0) wsum[wave] = w;
    __syncthreads();
    if (tid == 0) {
        float s = 0.f;
        #pragma unroll
        for (int i = 0; i < NWAVE; ++i) s += wsum[i];
        s_winv = 1.f / s;
    }
    __syncthreads();

    // ---- pass 2: weighted sum over 98 selected rows.
    // idx < 98 -> fp16 LDS stash; idx >= 98 -> global (L3-warm).
    // Row index is wave-uniform -> branch is wave-uniform. ----
    float4 acc_a = make_float4(0.f, 0.f, 0.f, 0.f);
    float4 acc_b = make_float4(0.f, 0.f, 0.f, 0.f);
    #pragma unroll
    for (int j = 0; j < 13; ++j) {
        const int i = wave + NWAVE * j;          // 0..103
        if (i < TK) {
            const int   r   = selIdx[i];
            const float wgt = selW[i];
            if (r < TK) {
                union { uint2 u; __half2 h[2]; } U;
                U.u = *(const uint2*)&feat16[r][4 * lane];
                float2 f0 = __half22float2(U.h[0]);
                float2 f1 = __half22float2(U.h[1]);
                acc_a.x += wgt * f0.x; acc_a.y += wgt * f0.y;
                acc_a.z += wgt * f1.x; acc_a.w += wgt * f1.y;
                if (lane < 32) {
                    union { uint2 u; __half2 h[2]; } V;
                    V.u = *(const uint2*)&feat16[r][256 + 4 * lane];
                    float2 g0 = __half22float2(V.h[0]);
                    float2 g1 = __half22float2(V.h[1]);
                    acc_b.x += wgt * g0.x; acc_b.y += wgt * g0.y;
                    acc_b.z += wgt * g1.x; acc_b.w += wgt * g1.y;
                }
            } else {
                const float4* f4 = f4base + (size_t)r * CF4;
                float4 aa = f4[lane];
                acc_a.x += wgt * aa.x; acc_a.y += wgt * aa.y;
                acc_a.z += wgt * aa.z; acc_a.w += wgt * aa.w;
                if (lane < 32) {
                    float4 bb = f4[64 + lane];
                    acc_b.x += wgt * bb.x; acc_b.y += wgt * bb.y;
                    acc_b.z += wgt * bb.z; acc_b.w += wgt * bb.w;
                }
            }
        }
    }
    // all stash reads complete before the region is reused for partials
    __syncthreads();

    float4* pw = (float4*)&part[wave][0];
    pw[lane] = acc_a;
    if (lane < 32) pw[64 + lane] = acc_b;
    __syncthreads();

    // ---- 8-way cross-wave reduction, coalesced store ----
    if (tid < C) {
        float s = 0.f;
        #pragma unroll
        for (int wv = 0; wv < NWAVE; ++wv) s += part[wv][tid];
        out[(size_t)pair * C + tid] = s * s_winv;
    }
}

extern "C" void kernel_launch(void* const* d_in, const int* in_sizes, int n_in,
                              void* d_out, int out_size, void* d_ws, size_t ws_size,
                              hipStream_t stream) {
    const float* token   = (const float*)d_in[0];
    const float* feature = (const float*)d_in[1];
    float* out = (float*)d_out;
    const int pairs = in_sizes[0] / C;   // 8*16*4 = 512
    sampling_kernel<<<pairs, NT, 0, stream>>>(token, feature, out);
}